// Round 10
// baseline (236.268 us; speedup 1.0000x reference)
//
#include <hip/hip_runtime.h>

#define FF 128
#define BCAP 8192       // per-bucket region capacity (avg ~4081 for seeded input)
#define CHUNK 4096      // edges per partA block
#define PITCH 136
#define BSTRIDE 32      // bucket_cnt padded: 1 counter per 128B line

typedef __attribute__((ext_vector_type(8))) short short8;
typedef __attribute__((ext_vector_type(4))) float f32x4;

__device__ __forceinline__ unsigned short bf16_rne(float f) {
    unsigned u = __float_as_uint(f);
    u += 0x7fffu + ((u >> 16) & 1u);
    return (unsigned short)(u >> 16);
}
__device__ __forceinline__ float bf16_to_f32(unsigned short h) {
    return __uint_as_float(((unsigned)h) << 16);
}

// Load one MFMA B-fragment (8 contiguous weights of row j starting at col k)
// from fp32 and split into bf16 hi/lo in-register (identical math to the old
// wprep kernel: hi = rne(f), lo = rne(f - hi)).
__device__ __forceinline__ void ldwsplit(const float* __restrict__ W, int j, int k,
                                         short8& hi, short8& lo) {
    const float4* p = (const float4*)&W[(size_t)j * FF + k];
    float4 q0 = p[0], q1 = p[1];
    float f[8] = {q0.x, q0.y, q0.z, q0.w, q1.x, q1.y, q1.z, q1.w};
    union { unsigned short u[8]; short8 s; } H, L;
    #pragma unroll
    for (int i = 0; i < 8; ++i) {
        unsigned short h = bf16_rne(f[i]);
        H.u[i] = h;
        L.u[i] = bf16_rne(f[i] - bf16_to_f32(h));
    }
    hi = H.s; lo = L.s;
}

// ---------------------------------------------------------------------------
// Fused partA + pool layer 0 (independent work, one dispatch):
//  - blocks [0, nchunks): LDS bucket partition of 4096-edge chunks
//  - blocks [nchunks, ...): pool tiles, folded L2-norm, h bf16 out (row-major)
//    Weights loaded as fp32 + split inline (no wprep stage).
// ---------------------------------------------------------------------------
__global__ __launch_bounds__(256, 2)
void poolpartA_kernel(const float* __restrict__ x,
                      const float* __restrict__ W,
                      const float* __restrict__ bias,
                      unsigned short* __restrict__ hout,
                      const int* __restrict__ esrc, const int* __restrict__ edst,
                      const float* __restrict__ eval,
                      int* __restrict__ bucket_cnt, int2* __restrict__ ebuf,
                      int N, int E, int nchunks)
{
    __shared__ alignas(16) char smem[37888];
    const int t = threadIdx.x;

    if (blockIdx.x < nchunks) {
        // ---------------- partA chunk ----------------
        int* cnt   = (int*)smem;
        int* sc    = cnt + 256;
        int* excl  = sc + 256;
        int* cur   = excl + 256;
        int* gbase = cur + 256;
        int2* staged = (int2*)(smem + 5 * 256 * 4);
        const int e0 = blockIdx.x * CHUNK;
        const int n  = min(CHUNK, E - e0);

        // register-stash all edges (one global read): packed {src16|dst16<<16}, val
        unsigned pk[16]; float vr[16];
        #pragma unroll
        for (int k = 0; k < 16; ++k) {
            const int i = t + k * 256;
            pk[k] = 0xFFFFFFFFu;
            if (i < n) {
                int d = edst[e0 + i];
                int s = esrc[e0 + i];
                pk[k] = (unsigned)((s & 0xffff) | (d << 16));
                vr[k] = eval[e0 + i];
            }
        }

        cnt[t] = 0;
        __syncthreads();
        #pragma unroll
        for (int k = 0; k < 16; ++k)
            if (pk[k] != 0xFFFFFFFFu) atomicAdd(&cnt[pk[k] >> 24], 1);
        __syncthreads();

        sc[t] = cnt[t];
        __syncthreads();
        #pragma unroll
        for (int off = 1; off < 256; off <<= 1) {
            int v = (t >= off) ? sc[t - off] : 0;
            __syncthreads();
            sc[t] += v;
            __syncthreads();
        }
        excl[t] = sc[t] - cnt[t];
        cur[t]  = excl[t];
        if (cnt[t] > 0) gbase[t] = atomicAdd(&bucket_cnt[t * BSTRIDE], cnt[t]);
        __syncthreads();

        #pragma unroll
        for (int k = 0; k < 16; ++k) {
            if (pk[k] != 0xFFFFFFFFu) {
                int b = pk[k] >> 24;
                int slot = atomicAdd(&cur[b], 1);
                staged[slot] = make_int2((int)pk[k], __float_as_int(vr[k]));
            }
        }
        __syncthreads();

        for (int p = t; p < n; p += 256) {
            int2 ent = staged[p];
            int b = ((unsigned)ent.x) >> 24;
            int gpos = gbase[b] + (p - excl[b]);
            ebuf[(size_t)b * BCAP + gpos] = ent;
        }
    } else {
        // ---------------- pool tile (layer 0, fp32 input) ----------------
        unsigned short* sX = (unsigned short*)smem;
        float* sNorm = (float*)(smem + 64 * PITCH * 2);
        const int tile = blockIdx.x - nchunks;

        const int lane = t & 63, wave = t >> 6;
        const int quad = lane >> 4, l16 = lane & 15;

        // weight fragments: fp32 load + inline split (L2 latency hides under
        // the x HBM staging below)
        short8 Bh[2][4], Bl[2][4];
        #pragma unroll
        for (int c = 0; c < 2; ++c) {
            const int j = (2 * wave + c) * 16 + l16;
            #pragma unroll
            for (int tt = 0; tt < 4; ++tt)
                ldwsplit(W, j, tt * 32 + quad * 8, Bh[c][tt], Bl[c][tt]);
        }

        #pragma unroll
        for (int rg = 0; rg < 2; ++rg) {
            const int row = rg * 32 + (t >> 3);
            const int c0  = (t & 7) * 16;
            const int n   = tile * 64 + row;
            const int base = row * PITCH + c0;
            float v[16];
            if (n < N) {
                const float4* p = (const float4*)(x + (size_t)n * FF + c0);
                #pragma unroll
                for (int i = 0; i < 4; ++i) {
                    float4 q = p[i];
                    v[4*i] = q.x; v[4*i+1] = q.y; v[4*i+2] = q.z; v[4*i+3] = q.w;
                }
            } else {
                #pragma unroll
                for (int i = 0; i < 16; ++i) v[i] = 0.f;
            }
            float ss = 0.f;
            #pragma unroll
            for (int i = 0; i < 16; ++i) ss = fmaf(v[i], v[i], ss);
            union { unsigned short u[8]; short8 s; } h0, h1;
            #pragma unroll
            for (int i = 0; i < 8; ++i) {
                h0.u[i] = bf16_rne(v[i]);
                h1.u[i] = bf16_rne(v[8 + i]);
            }
            *(short8*)&sX[base]     = h0.s;
            *(short8*)&sX[base + 8] = h1.s;
            ss += __shfl_xor(ss, 1);
            ss += __shfl_xor(ss, 2);
            ss += __shfl_xor(ss, 4);
            if ((t & 7) == 0) sNorm[row] = 1.0f / fmaxf(sqrtf(ss), 1e-12f);
        }
        __syncthreads();

        f32x4 acc[4][2];
        #pragma unroll
        for (int r = 0; r < 4; ++r)
            #pragma unroll
            for (int c = 0; c < 2; ++c) {
                f32x4 z = {0.f, 0.f, 0.f, 0.f};
                acc[r][c] = z;
            }

        #pragma unroll
        for (int tt = 0; tt < 4; ++tt) {
            short8 Ah[4];
            #pragma unroll
            for (int r = 0; r < 4; ++r)
                Ah[r] = *(const short8*)&sX[(r * 16 + l16) * PITCH + tt * 32 + quad * 8];
            #pragma unroll
            for (int c = 0; c < 2; ++c)
                #pragma unroll
                for (int r = 0; r < 4; ++r) {
                    acc[r][c] = __builtin_amdgcn_mfma_f32_16x16x32_bf16(Ah[r], Bh[c][tt], acc[r][c], 0, 0, 0);
                    acc[r][c] = __builtin_amdgcn_mfma_f32_16x16x32_bf16(Ah[r], Bl[c][tt], acc[r][c], 0, 0, 0);
                }
        }

        __syncthreads();   // all waves done reading sX fragments; reuse as h-stage
        #pragma unroll
        for (int c = 0; c < 2; ++c) {
            const int j = (2 * wave + c) * 16 + l16;
            const float bj = bias[j];
            #pragma unroll
            for (int r = 0; r < 4; ++r) {
                #pragma unroll
                for (int g = 0; g < 4; ++g) {
                    const int nl = r * 16 + quad * 4 + g;
                    float s = sNorm[nl];
                    float val = fmaf(acc[r][c][g], s, bj);
                    val = fmaxf(val, 0.f);
                    sX[nl * PITCH + j] = bf16_rne(val);
                }
            }
        }
        __syncthreads();
        #pragma unroll
        for (int rg = 0; rg < 2; ++rg) {
            const int row = rg * 32 + (t >> 3);
            const int c0  = (t & 7) * 16;
            const int n   = tile * 64 + row;
            if (n < N) {
                const int base = row * PITCH + c0;
                *(short8*)&hout[(size_t)n * FF + c0]     = *(short8*)&sX[base];
                *(short8*)&hout[(size_t)n * FF + c0 + 8] = *(short8*)&sX[base + 8];
            }
        }
    }
}

// ---------------------------------------------------------------------------
// Pass B: per-bucket fine sort (bucket read from L2; LDS cache removed —
// measured neutral in R4).
// ---------------------------------------------------------------------------
__global__ __launch_bounds__(256)
void partB_kernel(const int* __restrict__ bucket_cnt, const int2* __restrict__ ebuf,
                  int* __restrict__ offsets, int2* __restrict__ edata,
                  int N, int E, int nbuck)
{
    __shared__ int pre[256], hist[256], sc[256], excl[256], cur[256];
    const int t = threadIdx.x;
    const int b = blockIdx.x;

    pre[t] = (t < nbuck) ? bucket_cnt[t * BSTRIDE] : 0;
    hist[t] = 0;
    __syncthreads();
    #pragma unroll
    for (int off = 1; off < 256; off <<= 1) {
        int v = (t >= off) ? pre[t - off] : 0;
        __syncthreads();
        pre[t] += v;
        __syncthreads();
    }
    const int base = (b == 0) ? 0 : pre[b - 1];
    const int cnt  = pre[b] - base;

    const int2* ib = ebuf + (size_t)b * BCAP;
    for (int i = t; i < cnt; i += 256)
        atomicAdd(&hist[(((unsigned)ib[i].x) >> 16) & 255], 1);
    __syncthreads();

    sc[t] = hist[t];
    __syncthreads();
    #pragma unroll
    for (int off = 1; off < 256; off <<= 1) {
        int v = (t >= off) ? sc[t - off] : 0;
        __syncthreads();
        sc[t] += v;
        __syncthreads();
    }
    excl[t] = sc[t] - hist[t];
    cur[t]  = excl[t];

    const int node = b * 256 + t;
    if (node <= N) offsets[node] = base + excl[t];
    __syncthreads();

    for (int i = t; i < cnt; i += 256) {
        int2 ent = ib[i];
        int l = (((unsigned)ent.x) >> 16) & 255;
        int pos = base + atomicAdd(&cur[l], 1);
        edata[pos] = make_int2(ent.x & 0xffff, ent.y);
    }
}

// ---------------------------------------------------------------------------
// CSR aggregation, wave-per-node (zero divergence):
//   one wave64 owns one node; lane covers 2 feats (4 B) -> each edge's gather
//   is one fully coalesced 256 B row read. Wave index forced uniform via
//   readfirstlane so offsets/edata loads are SGPR-uniform (scalar SMEM path),
//   trip counts are wave-uniform -> no exec-mask drain replay.
// agg = sqrt(sum val*h[src]^2), squared in-register. Row-major planes.
// ---------------------------------------------------------------------------
__global__ __launch_bounds__(256)
void agg_kernel(const unsigned short* __restrict__ hp, const int* __restrict__ offsets,
                const int2* __restrict__ edata,
                unsigned short* __restrict__ aggh, int N)
{
    const int w = __builtin_amdgcn_readfirstlane(blockIdx.x * 4 + (threadIdx.x >> 6));
    if (w >= N) return;
    const int lane = threadIdx.x & 63;
    const int fo = lane * 2;

    int e = offsets[w];                     // uniform -> scalar load
    const int end = offsets[w + 1];

    float2 a0 = {0,0}, a1 = {0,0}, a2 = {0,0}, a3 = {0,0};

#define FMA1(A, V, U) { \
        float flo_ = __uint_as_float((U) << 16); \
        float fhi_ = __uint_as_float((U) & 0xffff0000u); \
        A.x = fmaf((V) * flo_, flo_, A.x); \
        A.y = fmaf((V) * fhi_, fhi_, A.y); }

    if ((e & 1) && e < end) {               // align to even for int4 meta loads
        int2 ed = edata[e];
        unsigned u = *(const unsigned*)&hp[(size_t)ed.x * FF + fo];
        FMA1(a0, __int_as_float(ed.y), u);
        ++e;
    }
    for (; e + 7 < end; e += 8) {           // 8 coalesced 256B gathers in flight
        int4 p0 = *(const int4*)&edata[e];
        int4 p1 = *(const int4*)&edata[e + 2];
        int4 p2 = *(const int4*)&edata[e + 4];
        int4 p3 = *(const int4*)&edata[e + 6];
        unsigned u0 = *(const unsigned*)&hp[(size_t)p0.x * FF + fo];
        unsigned u1 = *(const unsigned*)&hp[(size_t)p0.z * FF + fo];
        unsigned u2 = *(const unsigned*)&hp[(size_t)p1.x * FF + fo];
        unsigned u3 = *(const unsigned*)&hp[(size_t)p1.z * FF + fo];
        unsigned u4 = *(const unsigned*)&hp[(size_t)p2.x * FF + fo];
        unsigned u5 = *(const unsigned*)&hp[(size_t)p2.z * FF + fo];
        unsigned u6 = *(const unsigned*)&hp[(size_t)p3.x * FF + fo];
        unsigned u7 = *(const unsigned*)&hp[(size_t)p3.z * FF + fo];
        FMA1(a0, __int_as_float(p0.y), u0);
        FMA1(a1, __int_as_float(p0.w), u1);
        FMA1(a2, __int_as_float(p1.y), u2);
        FMA1(a3, __int_as_float(p1.w), u3);
        FMA1(a0, __int_as_float(p2.y), u4);
        FMA1(a1, __int_as_float(p2.w), u5);
        FMA1(a2, __int_as_float(p3.y), u6);
        FMA1(a3, __int_as_float(p3.w), u7);
    }
    if (e + 3 < end) {
        int4 p0 = *(const int4*)&edata[e];
        int4 p1 = *(const int4*)&edata[e + 2];
        unsigned u0 = *(const unsigned*)&hp[(size_t)p0.x * FF + fo];
        unsigned u1 = *(const unsigned*)&hp[(size_t)p0.z * FF + fo];
        unsigned u2 = *(const unsigned*)&hp[(size_t)p1.x * FF + fo];
        unsigned u3 = *(const unsigned*)&hp[(size_t)p1.z * FF + fo];
        FMA1(a0, __int_as_float(p0.y), u0);
        FMA1(a1, __int_as_float(p0.w), u1);
        FMA1(a2, __int_as_float(p1.y), u2);
        FMA1(a3, __int_as_float(p1.w), u3);
        e += 4;
    }
    if (e + 1 < end) {
        int4 p = *(const int4*)&edata[e];
        unsigned u0 = *(const unsigned*)&hp[(size_t)p.x * FF + fo];
        unsigned u1 = *(const unsigned*)&hp[(size_t)p.z * FF + fo];
        FMA1(a0, __int_as_float(p.y), u0);
        FMA1(a1, __int_as_float(p.w), u1);
        e += 2;
    }
    if (e < end) {
        int2 ed = edata[e];
        unsigned u = *(const unsigned*)&hp[(size_t)ed.x * FF + fo];
        FMA1(a0, __int_as_float(ed.y), u);
    }
#undef FMA1

    float rlo = sqrtf(a0.x + a1.x + a2.x + a3.x);
    float rhi = sqrtf(a0.y + a1.y + a2.y + a3.y);
    unsigned outw = (unsigned)bf16_rne(rlo) | ((unsigned)bf16_rne(rhi) << 16);
    *(unsigned*)&aggh[(size_t)w * FF + fo] = outw;
}

// ---------------------------------------------------------------------------
// Fused mm2 (layer 0) + pool (layer 1). Row-major inputs; x1 tile aliases the
// h tile (sH). fp32 weights loaded + split inline.
// ---------------------------------------------------------------------------
__global__ __launch_bounds__(256, 2)
void mm2pool_kernel(const unsigned short* __restrict__ hin,
                    const unsigned short* __restrict__ aggh,
                    const float* __restrict__ W1, const float* __restrict__ W2,
                    const float* __restrict__ b1, const float* __restrict__ b2,
                    const float* __restrict__ PW, const float* __restrict__ pb,
                    unsigned short* __restrict__ hout, int N)
{
    __shared__ unsigned short sH[64 * PITCH];   // h tile, then x1 tile
    __shared__ unsigned short sA[64 * PITCH];   // agg tile, then h2 stage
    __shared__ float sNorm[64];

    const int tid  = threadIdx.x;
    const int tile = blockIdx.x;
    const int lane = tid & 63, wave = tid >> 6;
    const int quad = lane >> 4, l16 = lane & 15;

    // ---- issue tile loads (HBM) into regs first ----
    short8 hreg[2][2], areg[2][2];
    #pragma unroll
    for (int rg = 0; rg < 2; ++rg) {
        const int row = rg * 32 + (tid >> 3);
        const int c0  = (tid & 7) * 16;
        const int n   = tile * 64 + row;
        short8 z = {0,0,0,0,0,0,0,0};
        hreg[rg][0] = z; hreg[rg][1] = z;
        areg[rg][0] = z; areg[rg][1] = z;
        if (n < N) {
            const short8* ph = (const short8*)(hin  + (size_t)n * FF + c0);
            const short8* pa = (const short8*)(aggh + (size_t)n * FF + c0);
            hreg[rg][0] = ph[0]; hreg[rg][1] = ph[1];
            areg[rg][0] = pa[0]; areg[rg][1] = pa[1];
        }
    }

    // ---- B-frag fp32 loads + inline split (overlap tile-load latency) ----
    short8 B1hf[2][4], B1lf[2][4], B2hf[2][4], B2lf[2][4];
    #pragma unroll
    for (int c = 0; c < 2; ++c) {
        const int j = (2 * wave + c) * 16 + l16;
        #pragma unroll
        for (int t = 0; t < 4; ++t) {
            const int k = t * 32 + quad * 8;
            ldwsplit(W1, j, k, B1hf[c][t], B1lf[c][t]);
            ldwsplit(W2, j, k, B2hf[c][t], B2lf[c][t]);
        }
    }

    // ---- write staged tiles ----
    #pragma unroll
    for (int rg = 0; rg < 2; ++rg) {
        const int row = rg * 32 + (tid >> 3);
        const int base = row * PITCH + (tid & 7) * 16;
        *(short8*)&sH[base]     = hreg[rg][0];
        *(short8*)&sH[base + 8] = hreg[rg][1];
        *(short8*)&sA[base]     = areg[rg][0];
        *(short8*)&sA[base + 8] = areg[rg][1];
    }
    __syncthreads();

    f32x4 acc[4][2];
    #pragma unroll
    for (int r = 0; r < 4; ++r)
        #pragma unroll
        for (int c = 0; c < 2; ++c) {
            f32x4 z = {0.f, 0.f, 0.f, 0.f};
            acc[r][c] = z;
        }

    #pragma unroll
    for (int t = 0; t < 4; ++t) {
        short8 Hf[4], AH[4];
        #pragma unroll
        for (int r = 0; r < 4; ++r) {
            const int off = (r * 16 + l16) * PITCH + t * 32 + quad * 8;
            Hf[r] = *(const short8*)&sH[off];
            AH[r] = *(const short8*)&sA[off];
        }
        #pragma unroll
        for (int c = 0; c < 2; ++c)
            #pragma unroll
            for (int r = 0; r < 4; ++r) {
                acc[r][c] = __builtin_amdgcn_mfma_f32_16x16x32_bf16(Hf[r], B1hf[c][t], acc[r][c], 0, 0, 0);
                acc[r][c] = __builtin_amdgcn_mfma_f32_16x16x32_bf16(Hf[r], B1lf[c][t], acc[r][c], 0, 0, 0);
                acc[r][c] = __builtin_amdgcn_mfma_f32_16x16x32_bf16(AH[r], B2hf[c][t], acc[r][c], 0, 0, 0);
                acc[r][c] = __builtin_amdgcn_mfma_f32_16x16x32_bf16(AH[r], B2lf[c][t], acc[r][c], 0, 0, 0);
            }
    }

    // ---- pool-weight fp32 loads + split: latency hides under x1 epilogue ----
    short8 Ph[2][4], Pl[2][4];
    #pragma unroll
    for (int c = 0; c < 2; ++c) {
        const int j = (2 * wave + c) * 16 + l16;
        #pragma unroll
        for (int t = 0; t < 4; ++t)
            ldwsplit(PW, j, t * 32 + quad * 8, Ph[c][t], Pl[c][t]);
    }

    __syncthreads();   // everyone done reading sH fragments -> reuse as x1 tile

    // ---------------- x1 = relu(mm2) -> bf16 tile in sH ----------------
    #pragma unroll
    for (int c = 0; c < 2; ++c) {
        const int j = (2 * wave + c) * 16 + l16;
        const float bj = b1[j] + b2[j];
        #pragma unroll
        for (int r = 0; r < 4; ++r) {
            #pragma unroll
            for (int g = 0; g < 4; ++g) {
                const int nl = r * 16 + quad * 4 + g;
                float val = fmaxf(acc[r][c][g] + bj, 0.f);
                sH[nl * PITCH + j] = bf16_rne(val);
            }
        }
    }
    __syncthreads();

    // ---------------- row L2-norms from the bf16 x1 tile ----------------
    #pragma unroll
    for (int rg = 0; rg < 2; ++rg) {
        const int row = rg * 32 + (tid >> 3);
        const int c0  = (tid & 7) * 16;
        union { short8 s; unsigned short u[8]; } a, b;
        a.s = *(short8*)&sH[row * PITCH + c0];
        b.s = *(short8*)&sH[row * PITCH + c0 + 8];
        float ss = 0.f;
        #pragma unroll
        for (int i = 0; i < 8; ++i) {
            float fa = bf16_to_f32(a.u[i]);
            float fb = bf16_to_f32(b.u[i]);
            ss = fmaf(fa, fa, fmaf(fb, fb, ss));
        }
        ss += __shfl_xor(ss, 1);
        ss += __shfl_xor(ss, 2);
        ss += __shfl_xor(ss, 4);
        if ((tid & 7) == 0) sNorm[row] = 1.0f / fmaxf(sqrtf(ss), 1e-12f);
    }
    __syncthreads();

    // ---------------- pool MFMA over x1 (norm folded in epilogue) ------
    f32x4 acc2[4][2];
    #pragma unroll
    for (int r = 0; r < 4; ++r)
        #pragma unroll
        for (int c = 0; c < 2; ++c) {
            f32x4 z = {0.f, 0.f, 0.f, 0.f};
            acc2[r][c] = z;
        }

    #pragma unroll
    for (int t = 0; t < 4; ++t) {
        short8 Ah[4];
        #pragma unroll
        for (int r = 0; r < 4; ++r)
            Ah[r] = *(const short8*)&sH[(r * 16 + l16) * PITCH + t * 32 + quad * 8];
        #pragma unroll
        for (int c = 0; c < 2; ++c)
            #pragma unroll
            for (int r = 0; r < 4; ++r) {
                acc2[r][c] = __builtin_amdgcn_mfma_f32_16x16x32_bf16(Ah[r], Ph[c][t], acc2[r][c], 0, 0, 0);
                acc2[r][c] = __builtin_amdgcn_mfma_f32_16x16x32_bf16(Ah[r], Pl[c][t], acc2[r][c], 0, 0, 0);
            }
    }

    __syncthreads();   // sA reads long done; reuse as h2 stage
    #pragma unroll
    for (int c = 0; c < 2; ++c) {
        const int j = (2 * wave + c) * 16 + l16;
        const float pbj = pb[j];
        #pragma unroll
        for (int r = 0; r < 4; ++r) {
            #pragma unroll
            for (int g = 0; g < 4; ++g) {
                const int nl = r * 16 + quad * 4 + g;
                float s = sNorm[nl];
                float val = fmaxf(fmaf(acc2[r][c][g], s, pbj), 0.f);
                sA[nl * PITCH + j] = bf16_rne(val);
            }
        }
    }
    __syncthreads();
    #pragma unroll
    for (int rg = 0; rg < 2; ++rg) {
        const int row = rg * 32 + (tid >> 3);
        const int c0  = (tid & 7) * 16;
        const int n   = tile * 64 + row;
        if (n < N) {
            const int base = row * PITCH + c0;
            *(short8*)&hout[(size_t)n * FF + c0]     = *(short8*)&sA[base];
            *(short8*)&hout[(size_t)n * FF + c0 + 8] = *(short8*)&sA[base + 8];
        }
    }
}

// ---------------------------------------------------------------------------
// Final mm2 (layer 1): out[n][j] = h@W1 + agg@W2 + b1+b2, fp32, LDS-staged
// coalesced stores. Row-major inputs; fp32 weights split inline.
// ---------------------------------------------------------------------------
#define OPITCH 68
__global__ __launch_bounds__(256, 2)
void mm2_final_kernel(const unsigned short* __restrict__ hin,
                      const unsigned short* __restrict__ aggh,
                      const float* __restrict__ W1, const float* __restrict__ W2,
                      const float* __restrict__ b1, const float* __restrict__ b2,
                      float* __restrict__ out, int N)
{
    __shared__ unsigned short sH[64 * PITCH];
    __shared__ unsigned short sA[64 * PITCH];

    const int tid  = threadIdx.x;
    const int tile = blockIdx.x;
    const int lane = tid & 63, wave = tid >> 6;
    const int quad = lane >> 4, l16 = lane & 15;

    // ---- tile loads into regs first ----
    short8 hreg[2][2], areg[2][2];
    #pragma unroll
    for (int rg = 0; rg < 2; ++rg) {
        const int row = rg * 32 + (tid >> 3);
        const int c0  = (tid & 7) * 16;
        const int n   = tile * 64 + row;
        short8 z = {0,0,0,0,0,0,0,0};
        hreg[rg][0] = z; hreg[rg][1] = z;
        areg[rg][0] = z; areg[rg][1] = z;
        if (n < N) {
            const short8* ph = (const short8*)(hin  + (size_t)n * FF + c0);
            const short8* pa = (const short8*)(aggh + (size_t)n * FF + c0);
            hreg[rg][0] = ph[0]; hreg[rg][1] = ph[1];
            areg[rg][0] = pa[0]; areg[rg][1] = pa[1];
        }
    }

    // ---- B-frag fp32 loads + inline split (overlap tile-load latency) ----
    short8 B1hf[4], B1lf[4], B2hf[4], B2lf[4];
    {
        const int j = wave * 16 + l16;
        #pragma unroll
        for (int t = 0; t < 4; ++t) {
            const int k = t * 32 + quad * 8;
            ldwsplit(W1, j, k, B1hf[t], B1lf[t]);
            ldwsplit(W2, j, k, B2hf[t], B2lf[t]);
        }
    }

    #pragma unroll
    for (int rg = 0; rg < 2; ++rg) {
        const int row = rg * 32 + (tid >> 3);
        const int base = row * PITCH + (tid & 7) * 16;
        *(short8*)&sH[base]     = hreg[rg][0];
        *(short8*)&sH[base + 8] = hreg[rg][1];
        *(short8*)&sA[base]     = areg[rg][0];
        *(short8*)&sA[base + 8] = areg[rg][1];
    }
    __syncthreads();

    f32x4 acc[4];
    #pragma unroll
    for (int r = 0; r < 4; ++r) {
        f32x4 z = {0.f, 0.f, 0.f, 0.f};
        acc[r] = z;
    }

    #pragma unroll
    for (int t = 0; t < 4; ++t) {
        short8 Hf[4], AH[4];
        #pragma unroll
        for (int r = 0; r < 4; ++r) {
            const int off = (r * 16 + l16) * PITCH + t * 32 + quad * 8;
            Hf[r] = *(const short8*)&sH[off];
            AH[r] = *(const short8*)&sA[off];
        }
        #pragma unroll
        for (int r = 0; r < 4; ++r) {
            acc[r] = __builtin_amdgcn_mfma_f32_16x16x32_bf16(Hf[r], B1hf[t], acc[r], 0, 0, 0);
            acc[r] = __builtin_amdgcn_mfma_f32_16x16x32_bf16(Hf[r], B1lf[t], acc[r], 0, 0, 0);
            acc[r] = __builtin_amdgcn_mfma_f32_16x16x32_bf16(AH[r], B2hf[t], acc[r], 0, 0, 0);
            acc[r] = __builtin_amdgcn_mfma_f32_16x16x32_bf16(AH[r], B2lf[t], acc[r], 0, 0, 0);
        }
    }

    __syncthreads();
    float* sOut = (float*)sH;
    {
        const int j = wave * 16 + l16;
        const float bj = b1[j] + b2[j];
        #pragma unroll
        for (int r = 0; r < 4; ++r) {
            #pragma unroll
            for (int g = 0; g < 4; ++g) {
                const int nl = r * 16 + quad * 4 + g;
                sOut[nl * OPITCH + j] = acc[r][g] + bj;
            }
        }
    }
    __syncthreads();
    {
        const int row = tid >> 2;
        const int seg = tid & 3;
        const int n = tile * 64 + row;
        if (n < N) {
            const float4* src = (const float4*)&sOut[row * OPITCH + seg * 16];
            float4* dst = (float4*)&out[(size_t)n * 64 + seg * 16];
            #pragma unroll
            for (int i = 0; i < 4; ++i) dst[i] = src[i];
        }
    }
}

// ---------------------------------------------------------------------------
extern "C" void kernel_launch(void* const* d_in, const int* in_sizes, int n_in,
                              void* d_out, int out_size, void* d_ws, size_t ws_size,
                              hipStream_t stream) {
    const float* x    = (const float*)d_in[0];
    const int*   esrc = (const int*)d_in[1];
    const int*   edst = (const int*)d_in[2];
    const float* eval = (const float*)d_in[3];
    const float* pw0  = (const float*)d_in[4];
    const float* pb0  = (const float*)d_in[5];
    const float* f1w0 = (const float*)d_in[6];
    const float* f1b0 = (const float*)d_in[7];
    const float* f2w0 = (const float*)d_in[8];
    const float* f2b0 = (const float*)d_in[9];
    const float* pw1  = (const float*)d_in[10];
    const float* pb1  = (const float*)d_in[11];
    const float* f1w1 = (const float*)d_in[12];
    const float* f1b1 = (const float*)d_in[13];
    const float* f2w1 = (const float*)d_in[14];
    const float* f2b1 = (const float*)d_in[15];
    float* out = (float*)d_out;

    const int N = in_sizes[0] / FF;     // 50000  (must be <= 65536 for 16-bit packing)
    const int E = in_sizes[1];          // 800000
    const int nbuck = (N + 255) / 256;  // 196

    char* ws = (char*)d_ws;
    const size_t planesz = (size_t)N * FF * 2;                    // 12.8 MB bf16 plane
    const size_t A = 256;
    size_t off = 0;
    unsigned short* h    = (unsigned short*)(ws + off); off += (planesz + A - 1) / A * A;
    unsigned short* h2   = (unsigned short*)(ws + off); off += (planesz + A - 1) / A * A;
    unsigned short* aggh = (unsigned short*)(ws + off); off += (planesz + A - 1) / A * A;
    int* offsets = (int*)(ws + off); off += ((size_t)(N + 1) * 4 + A - 1) / A * A;
    int* bucket_cnt = (int*)(ws + off); off += (size_t)256 * BSTRIDE * 4;
    int2* ebuf  = (int2*)(ws + off); off += (size_t)nbuck * BCAP * 8;   // 12.8 MB
    int2* edata = (int2*)(ws + off); off += (size_t)E * 8;

    const int ntiles     = (N + 63) / 64;
    const int nodeblocks = (N + 3) / 4;           // 4 waves/block, 1 node per wave
    const int nchunks    = (E + CHUNK - 1) / CHUNK;
    dim3 B(256);

    // ---- 0: zero padded bucket counters (graph-capturable async memset) ----
    hipMemsetAsync(bucket_cnt, 0, (size_t)256 * BSTRIDE * 4, stream);

    // ---- 1: fused partA + pool layer 0 -> h (row-major), ebuf ----
    poolpartA_kernel<<<nchunks + ntiles, B, 0, stream>>>(
        x, pw0, pb0, h, esrc, edst, eval, bucket_cnt, ebuf, N, E, nchunks);

    // ---- 2: partB (dst-sorted edata + offsets) ----
    partB_kernel<<<nbuck, B, 0, stream>>>(bucket_cnt, ebuf, offsets, edata, N, E, nbuck);

    // ---- 3: agg layer 0 (wave-per-node, zero divergence) ----
    agg_kernel<<<nodeblocks, B, 0, stream>>>(h, offsets, edata, aggh, N);

    // ---- 4: fused mm2 layer 0 + pool layer 1 -> h2 ----
    mm2pool_kernel<<<ntiles, B, 0, stream>>>(
        h, aggh, f1w0, f2w0, f1b0, f2b0, pw1, pb1, h2, N);

    // ---- 5: agg layer 1 ----
    agg_kernel<<<nodeblocks, B, 0, stream>>>(h2, offsets, edata, aggh, N);

    // ---- 6: final mm2 layer 1 -> out (fp32) ----
    mm2_final_kernel<<<ntiles, B, 0, stream>>>(
        h2, aggh, f1w1, f2w1, f1b1, f2b1, out, N);
}

// Round 11
// 217.192 us; speedup vs baseline: 1.0878x; 1.0878x over previous
//
#include <hip/hip_runtime.h>

#define FF 128
#define BCAP 8192       // per-bucket region capacity (avg ~4081 for seeded input)
#define CHUNK 4096      // edges per partA block
#define PITCH 136
#define BSTRIDE 32      // bucket_cnt padded: 1 counter per 128B line
#define PBCACHE 6144    // partB LDS bucket cache entries (48 KB)

typedef __attribute__((ext_vector_type(8))) short short8;
typedef __attribute__((ext_vector_type(4))) float f32x4;

__device__ __forceinline__ unsigned short bf16_rne(float f) {
    unsigned u = __float_as_uint(f);
    u += 0x7fffu + ((u >> 16) & 1u);
    return (unsigned short)(u >> 16);
}
__device__ __forceinline__ float bf16_to_f32(unsigned short h) {
    return __uint_as_float(((unsigned)h) << 16);
}

// ---------------------------------------------------------------------------
// Fused partA + pool layer 0 (independent work, one dispatch):
//  - blocks [0, nchunks): LDS bucket partition of 4096-edge chunks
//  - blocks [nchunks, ...): pool tiles, folded L2-norm, h bf16 out (row-major)
//    (weight-fragment loads hoisted above the staging barrier: L2 latency
//     overlaps the fp32 x HBM staging)
// ---------------------------------------------------------------------------
__global__ __launch_bounds__(256, 2)
void poolpartA_kernel(const float* __restrict__ x,
                      const unsigned short* __restrict__ Wh, const unsigned short* __restrict__ Wl,
                      const float* __restrict__ bias,
                      unsigned short* __restrict__ hout,
                      const int* __restrict__ esrc, const int* __restrict__ edst,
                      const float* __restrict__ eval,
                      int* __restrict__ bucket_cnt, int2* __restrict__ ebuf,
                      int N, int E, int nchunks)
{
    __shared__ alignas(16) char smem[37888];
    const int t = threadIdx.x;

    if (blockIdx.x < nchunks) {
        // ---------------- partA chunk ----------------
        int* cnt   = (int*)smem;
        int* sc    = cnt + 256;
        int* excl  = sc + 256;
        int* cur   = excl + 256;
        int* gbase = cur + 256;
        int2* staged = (int2*)(smem + 5 * 256 * 4);
        const int e0 = blockIdx.x * CHUNK;
        const int n  = min(CHUNK, E - e0);

        // register-stash all edges (one global read): packed {src16|dst16<<16}, val
        unsigned pk[16]; float vr[16];
        #pragma unroll
        for (int k = 0; k < 16; ++k) {
            const int i = t + k * 256;
            pk[k] = 0xFFFFFFFFu;
            if (i < n) {
                int d = edst[e0 + i];
                int s = esrc[e0 + i];
                pk[k] = (unsigned)((s & 0xffff) | (d << 16));
                vr[k] = eval[e0 + i];
            }
        }

        cnt[t] = 0;
        __syncthreads();
        #pragma unroll
        for (int k = 0; k < 16; ++k)
            if (pk[k] != 0xFFFFFFFFu) atomicAdd(&cnt[pk[k] >> 24], 1);
        __syncthreads();

        sc[t] = cnt[t];
        __syncthreads();
        #pragma unroll
        for (int off = 1; off < 256; off <<= 1) {
            int v = (t >= off) ? sc[t - off] : 0;
            __syncthreads();
            sc[t] += v;
            __syncthreads();
        }
        excl[t] = sc[t] - cnt[t];
        cur[t]  = excl[t];
        if (cnt[t] > 0) gbase[t] = atomicAdd(&bucket_cnt[t * BSTRIDE], cnt[t]);
        __syncthreads();

        #pragma unroll
        for (int k = 0; k < 16; ++k) {
            if (pk[k] != 0xFFFFFFFFu) {
                int b = pk[k] >> 24;
                int slot = atomicAdd(&cur[b], 1);
                staged[slot] = make_int2((int)pk[k], __float_as_int(vr[k]));
            }
        }
        __syncthreads();

        for (int p = t; p < n; p += 256) {
            int2 ent = staged[p];
            int b = ((unsigned)ent.x) >> 24;
            int gpos = gbase[b] + (p - excl[b]);
            ebuf[(size_t)b * BCAP + gpos] = ent;
        }
    } else {
        // ---------------- pool tile (layer 0, fp32 input) ----------------
        unsigned short* sX = (unsigned short*)smem;
        float* sNorm = (float*)(smem + 64 * PITCH * 2);
        const int tile = blockIdx.x - nchunks;

        const int lane = t & 63, wave = t >> 6;
        const int quad = lane >> 4, l16 = lane & 15;

        // weight fragments: issue early (L2) so latency hides under x staging
        short8 Bh[2][4], Bl[2][4];
        #pragma unroll
        for (int c = 0; c < 2; ++c) {
            const int jt = 2 * wave + c;
            #pragma unroll
            for (int tt = 0; tt < 4; ++tt) {
                const size_t o = ((size_t)(jt * 4 + tt) * 64 + lane) * 8;
                Bh[c][tt] = *(const short8*)&Wh[o];
                Bl[c][tt] = *(const short8*)&Wl[o];
            }
        }

        #pragma unroll
        for (int rg = 0; rg < 2; ++rg) {
            const int row = rg * 32 + (t >> 3);
            const int c0  = (t & 7) * 16;
            const int n   = tile * 64 + row;
            const int base = row * PITCH + c0;
            float v[16];
            if (n < N) {
                const float4* p = (const float4*)(x + (size_t)n * FF + c0);
                #pragma unroll
                for (int i = 0; i < 4; ++i) {
                    float4 q = p[i];
                    v[4*i] = q.x; v[4*i+1] = q.y; v[4*i+2] = q.z; v[4*i+3] = q.w;
                }
            } else {
                #pragma unroll
                for (int i = 0; i < 16; ++i) v[i] = 0.f;
            }
            float ss = 0.f;
            #pragma unroll
            for (int i = 0; i < 16; ++i) ss = fmaf(v[i], v[i], ss);
            union { unsigned short u[8]; short8 s; } h0, h1;
            #pragma unroll
            for (int i = 0; i < 8; ++i) {
                h0.u[i] = bf16_rne(v[i]);
                h1.u[i] = bf16_rne(v[8 + i]);
            }
            *(short8*)&sX[base]     = h0.s;
            *(short8*)&sX[base + 8] = h1.s;
            ss += __shfl_xor(ss, 1);
            ss += __shfl_xor(ss, 2);
            ss += __shfl_xor(ss, 4);
            if ((t & 7) == 0) sNorm[row] = 1.0f / fmaxf(sqrtf(ss), 1e-12f);
        }
        __syncthreads();

        f32x4 acc[4][2];
        #pragma unroll
        for (int r = 0; r < 4; ++r)
            #pragma unroll
            for (int c = 0; c < 2; ++c) {
                f32x4 z = {0.f, 0.f, 0.f, 0.f};
                acc[r][c] = z;
            }

        #pragma unroll
        for (int tt = 0; tt < 4; ++tt) {
            short8 Ah[4];
            #pragma unroll
            for (int r = 0; r < 4; ++r)
                Ah[r] = *(const short8*)&sX[(r * 16 + l16) * PITCH + tt * 32 + quad * 8];
            #pragma unroll
            for (int c = 0; c < 2; ++c)
                #pragma unroll
                for (int r = 0; r < 4; ++r) {
                    acc[r][c] = __builtin_amdgcn_mfma_f32_16x16x32_bf16(Ah[r], Bh[c][tt], acc[r][c], 0, 0, 0);
                    acc[r][c] = __builtin_amdgcn_mfma_f32_16x16x32_bf16(Ah[r], Bl[c][tt], acc[r][c], 0, 0, 0);
                }
        }

        __syncthreads();   // all waves done reading sX fragments; reuse as h-stage
        #pragma unroll
        for (int c = 0; c < 2; ++c) {
            const int j = (2 * wave + c) * 16 + l16;
            const float bj = bias[j];
            #pragma unroll
            for (int r = 0; r < 4; ++r) {
                #pragma unroll
                for (int g = 0; g < 4; ++g) {
                    const int nl = r * 16 + quad * 4 + g;
                    float s = sNorm[nl];
                    float val = fmaf(acc[r][c][g], s, bj);
                    val = fmaxf(val, 0.f);
                    sX[nl * PITCH + j] = bf16_rne(val);
                }
            }
        }
        __syncthreads();
        #pragma unroll
        for (int rg = 0; rg < 2; ++rg) {
            const int row = rg * 32 + (t >> 3);
            const int c0  = (t & 7) * 16;
            const int n   = tile * 64 + row;
            if (n < N) {
                const int base = row * PITCH + c0;
                *(short8*)&hout[(size_t)n * FF + c0]     = *(short8*)&sX[base];
                *(short8*)&hout[(size_t)n * FF + c0 + 8] = *(short8*)&sX[base + 8];
            }
        }
    }
}

// ---------------------------------------------------------------------------
// Weight prep: fp32 [OUT][128] -> fragment-major bf16 hi/lo planes.
// Block 0 also zeroes (padded) bucket_cnt.
// (Kept as a separate stage: fragment-major planes give perfectly coalesced
//  wave loads in the MFMA kernels — R10 measured inline fp32 split as −18 µs.)
// ---------------------------------------------------------------------------
struct WPack {
    const float* src[6];
    unsigned short* hi[6];
    unsigned short* lo[6];
    int n[6];
};

__global__ __launch_bounds__(256)
void wprep_kernel(WPack p, int* __restrict__ bucket_cnt)
{
    if (blockIdx.x == 0) {
        for (int i = threadIdx.x; i < 256 * BSTRIDE; i += 256) bucket_cnt[i] = 0;
    }
    int id = blockIdx.x * 256 + threadIdx.x;
    #pragma unroll
    for (int i = 0; i < 6; ++i) {
        if (id < p.n[i]) {
            float f = p.src[i][id];
            unsigned short h = bf16_rne(f);
            const int j = id >> 7, k = id & 127;
            const int jt = j >> 4, l16 = j & 15;
            const int t = k >> 5, quad = (k >> 3) & 3, j8 = k & 7;
            const size_t o = ((size_t)((jt * 4 + t) * 4 + quad) * 16 + l16) * 8 + j8;
            p.hi[i][o] = h;
            p.lo[i][o] = bf16_rne(f - bf16_to_f32(h));
            return;
        }
        id -= p.n[i];
    }
}

// ---------------------------------------------------------------------------
// Pass B: per-bucket fine sort, bucket cached in LDS (one global read).
// ---------------------------------------------------------------------------
__global__ __launch_bounds__(256)
void partB_kernel(const int* __restrict__ bucket_cnt, const int2* __restrict__ ebuf,
                  int* __restrict__ offsets, int2* __restrict__ edata,
                  int N, int E, int nbuck)
{
    __shared__ int pre[256], hist[256], sc[256], excl[256], cur[256];
    __shared__ int2 sBuf[PBCACHE];
    const int t = threadIdx.x;
    const int b = blockIdx.x;

    const int cnt_self = bucket_cnt[b * BSTRIDE];
    const int2* ib = ebuf + (size_t)b * BCAP;
    const bool useL = (cnt_self <= PBCACHE);

    // start LDS bucket load (overlaps the base prescan below)
    if (useL)
        for (int i = t; i < cnt_self; i += 256) sBuf[i] = ib[i];

    pre[t] = (t < nbuck) ? bucket_cnt[t * BSTRIDE] : 0;
    hist[t] = 0;
    __syncthreads();
    #pragma unroll
    for (int off = 1; off < 256; off <<= 1) {
        int v = (t >= off) ? pre[t - off] : 0;
        __syncthreads();
        pre[t] += v;
        __syncthreads();
    }
    const int base = (b == 0) ? 0 : pre[b - 1];
    const int cnt  = cnt_self;

    for (int i = t; i < cnt; i += 256) {
        int2 ent = useL ? sBuf[i] : ib[i];
        atomicAdd(&hist[(((unsigned)ent.x) >> 16) & 255], 1);
    }
    __syncthreads();

    sc[t] = hist[t];
    __syncthreads();
    #pragma unroll
    for (int off = 1; off < 256; off <<= 1) {
        int v = (t >= off) ? sc[t - off] : 0;
        __syncthreads();
        sc[t] += v;
        __syncthreads();
    }
    excl[t] = sc[t] - hist[t];
    cur[t]  = excl[t];

    const int node = b * 256 + t;
    if (node <= N) offsets[node] = base + excl[t];
    __syncthreads();

    for (int i = t; i < cnt; i += 256) {
        int2 ent = useL ? sBuf[i] : ib[i];
        int l = (((unsigned)ent.x) >> 16) & 255;
        int pos = base + atomicAdd(&cur[l], 1);
        edata[pos] = make_int2(ent.x & 0xffff, ent.y);
    }
}

// ---------------------------------------------------------------------------
// CSR aggregation, wave-per-node (zero divergence):
//   one wave64 owns one node; lane covers 2 feats (4 B) -> each edge's gather
//   is one fully coalesced 256 B row read. Wave index forced uniform via
//   readfirstlane so offsets/edata loads are SGPR-uniform (scalar SMEM path),
//   trip counts are wave-uniform -> no exec-mask drain replay.
// agg = sqrt(sum val*h[src]^2), squared in-register. Row-major planes.
// ---------------------------------------------------------------------------
__global__ __launch_bounds__(256)
void agg_kernel(const unsigned short* __restrict__ hp, const int* __restrict__ offsets,
                const int2* __restrict__ edata,
                unsigned short* __restrict__ aggh, int N)
{
    const int w = __builtin_amdgcn_readfirstlane(blockIdx.x * 4 + (threadIdx.x >> 6));
    if (w >= N) return;
    const int lane = threadIdx.x & 63;
    const int fo = lane * 2;

    int e = offsets[w];                     // uniform -> scalar load
    const int end = offsets[w + 1];

    float2 a0 = {0,0}, a1 = {0,0}, a2 = {0,0}, a3 = {0,0};

#define FMA1(A, V, U) { \
        float flo_ = __uint_as_float((U) << 16); \
        float fhi_ = __uint_as_float((U) & 0xffff0000u); \
        A.x = fmaf((V) * flo_, flo_, A.x); \
        A.y = fmaf((V) * fhi_, fhi_, A.y); }

    if ((e & 1) && e < end) {               // align to even for int4 meta loads
        int2 ed = edata[e];
        unsigned u = *(const unsigned*)&hp[(size_t)ed.x * FF + fo];
        FMA1(a0, __int_as_float(ed.y), u);
        ++e;
    }
    for (; e + 7 < end; e += 8) {           // 8 coalesced 256B gathers in flight
        int4 p0 = *(const int4*)&edata[e];
        int4 p1 = *(const int4*)&edata[e + 2];
        int4 p2 = *(const int4*)&edata[e + 4];
        int4 p3 = *(const int4*)&edata[e + 6];
        unsigned u0 = *(const unsigned*)&hp[(size_t)p0.x * FF + fo];
        unsigned u1 = *(const unsigned*)&hp[(size_t)p0.z * FF + fo];
        unsigned u2 = *(const unsigned*)&hp[(size_t)p1.x * FF + fo];
        unsigned u3 = *(const unsigned*)&hp[(size_t)p1.z * FF + fo];
        unsigned u4 = *(const unsigned*)&hp[(size_t)p2.x * FF + fo];
        unsigned u5 = *(const unsigned*)&hp[(size_t)p2.z * FF + fo];
        unsigned u6 = *(const unsigned*)&hp[(size_t)p3.x * FF + fo];
        unsigned u7 = *(const unsigned*)&hp[(size_t)p3.z * FF + fo];
        FMA1(a0, __int_as_float(p0.y), u0);
        FMA1(a1, __int_as_float(p0.w), u1);
        FMA1(a2, __int_as_float(p1.y), u2);
        FMA1(a3, __int_as_float(p1.w), u3);
        FMA1(a0, __int_as_float(p2.y), u4);
        FMA1(a1, __int_as_float(p2.w), u5);
        FMA1(a2, __int_as_float(p3.y), u6);
        FMA1(a3, __int_as_float(p3.w), u7);
    }
    if (e + 3 < end) {
        int4 p0 = *(const int4*)&edata[e];
        int4 p1 = *(const int4*)&edata[e + 2];
        unsigned u0 = *(const unsigned*)&hp[(size_t)p0.x * FF + fo];
        unsigned u1 = *(const unsigned*)&hp[(size_t)p0.z * FF + fo];
        unsigned u2 = *(const unsigned*)&hp[(size_t)p1.x * FF + fo];
        unsigned u3 = *(const unsigned*)&hp[(size_t)p1.z * FF + fo];
        FMA1(a0, __int_as_float(p0.y), u0);
        FMA1(a1, __int_as_float(p0.w), u1);
        FMA1(a2, __int_as_float(p1.y), u2);
        FMA1(a3, __int_as_float(p1.w), u3);
        e += 4;
    }
    if (e + 1 < end) {
        int4 p = *(const int4*)&edata[e];
        unsigned u0 = *(const unsigned*)&hp[(size_t)p.x * FF + fo];
        unsigned u1 = *(const unsigned*)&hp[(size_t)p.z * FF + fo];
        FMA1(a0, __int_as_float(p.y), u0);
        FMA1(a1, __int_as_float(p.w), u1);
        e += 2;
    }
    if (e < end) {
        int2 ed = edata[e];
        unsigned u = *(const unsigned*)&hp[(size_t)ed.x * FF + fo];
        FMA1(a0, __int_as_float(ed.y), u);
    }
#undef FMA1

    float rlo = sqrtf(a0.x + a1.x + a2.x + a3.x);
    float rhi = sqrtf(a0.y + a1.y + a2.y + a3.y);
    unsigned outw = (unsigned)bf16_rne(rlo) | ((unsigned)bf16_rne(rhi) << 16);
    *(unsigned*)&aggh[(size_t)w * FF + fo] = outw;
}

// ---------------------------------------------------------------------------
// Fused mm2 (layer 0) + pool (layer 1). Row-major inputs; x1 tile aliases the
// h tile (sH). T14 stage split: tile loads -> B-frag loads -> LDS writes.
// ---------------------------------------------------------------------------
__global__ __launch_bounds__(256, 2)
void mm2pool_kernel(const unsigned short* __restrict__ hin,
                    const unsigned short* __restrict__ aggh,
                    const unsigned short* __restrict__ W1h, const unsigned short* __restrict__ W1l,
                    const unsigned short* __restrict__ W2h, const unsigned short* __restrict__ W2l,
                    const float* __restrict__ b1, const float* __restrict__ b2,
                    const unsigned short* __restrict__ PWh, const unsigned short* __restrict__ PWl,
                    const float* __restrict__ pb,
                    unsigned short* __restrict__ hout, int N)
{
    __shared__ unsigned short sH[64 * PITCH];   // h tile, then x1 tile
    __shared__ unsigned short sA[64 * PITCH];   // agg tile, then h2 stage
    __shared__ float sNorm[64];

    const int tid  = threadIdx.x;
    const int tile = blockIdx.x;
    const int lane = tid & 63, wave = tid >> 6;
    const int quad = lane >> 4, l16 = lane & 15;

    // ---- T14: issue tile loads (HBM) into regs first ----
    short8 hreg[2][2], areg[2][2];
    #pragma unroll
    for (int rg = 0; rg < 2; ++rg) {
        const int row = rg * 32 + (tid >> 3);
        const int c0  = (tid & 7) * 16;
        const int n   = tile * 64 + row;
        short8 z = {0,0,0,0,0,0,0,0};
        hreg[rg][0] = z; hreg[rg][1] = z;
        areg[rg][0] = z; areg[rg][1] = z;
        if (n < N) {
            const short8* ph = (const short8*)(hin  + (size_t)n * FF + c0);
            const short8* pa = (const short8*)(aggh + (size_t)n * FF + c0);
            hreg[rg][0] = ph[0]; hreg[rg][1] = ph[1];
            areg[rg][0] = pa[0]; areg[rg][1] = pa[1];
        }
    }

    // ---- B-frag loads (L2) overlap the tile-load latency ----
    short8 B1hf[2][4], B1lf[2][4], B2hf[2][4], B2lf[2][4];
    #pragma unroll
    for (int c = 0; c < 2; ++c) {
        const int jt = 2 * wave + c;
        #pragma unroll
        for (int t = 0; t < 4; ++t) {
            const size_t o = ((size_t)(jt * 4 + t) * 64 + lane) * 8;
            B1hf[c][t] = *(const short8*)&W1h[o];
            B1lf[c][t] = *(const short8*)&W1l[o];
            B2hf[c][t] = *(const short8*)&W2h[o];
            B2lf[c][t] = *(const short8*)&W2l[o];
        }
    }

    // ---- write staged tiles ----
    #pragma unroll
    for (int rg = 0; rg < 2; ++rg) {
        const int row = rg * 32 + (tid >> 3);
        const int base = row * PITCH + (tid & 7) * 16;
        *(short8*)&sH[base]     = hreg[rg][0];
        *(short8*)&sH[base + 8] = hreg[rg][1];
        *(short8*)&sA[base]     = areg[rg][0];
        *(short8*)&sA[base + 8] = areg[rg][1];
    }
    __syncthreads();

    f32x4 acc[4][2];
    #pragma unroll
    for (int r = 0; r < 4; ++r)
        #pragma unroll
        for (int c = 0; c < 2; ++c) {
            f32x4 z = {0.f, 0.f, 0.f, 0.f};
            acc[r][c] = z;
        }

    #pragma unroll
    for (int t = 0; t < 4; ++t) {
        short8 Hf[4], AH[4];
        #pragma unroll
        for (int r = 0; r < 4; ++r) {
            const int off = (r * 16 + l16) * PITCH + t * 32 + quad * 8;
            Hf[r] = *(const short8*)&sH[off];
            AH[r] = *(const short8*)&sA[off];
        }
        #pragma unroll
        for (int c = 0; c < 2; ++c)
            #pragma unroll
            for (int r = 0; r < 4; ++r) {
                acc[r][c] = __builtin_amdgcn_mfma_f32_16x16x32_bf16(Hf[r], B1hf[c][t], acc[r][c], 0, 0, 0);
                acc[r][c] = __builtin_amdgcn_mfma_f32_16x16x32_bf16(Hf[r], B1lf[c][t], acc[r][c], 0, 0, 0);
                acc[r][c] = __builtin_amdgcn_mfma_f32_16x16x32_bf16(AH[r], B2hf[c][t], acc[r][c], 0, 0, 0);
                acc[r][c] = __builtin_amdgcn_mfma_f32_16x16x32_bf16(AH[r], B2lf[c][t], acc[r][c], 0, 0, 0);
            }
    }

    // ---- pool-weight loads issued here: L2 latency hides under the x1
    //      epilogue + norm phases ----
    short8 Ph[2][4], Pl[2][4];
    #pragma unroll
    for (int c = 0; c < 2; ++c) {
        const int jt = 2 * wave + c;
        #pragma unroll
        for (int t = 0; t < 4; ++t) {
            const size_t o = ((size_t)(jt * 4 + t) * 64 + lane) * 8;
            Ph[c][t] = *(const short8*)&PWh[o];
            Pl[c][t] = *(const short8*)&PWl[o];
        }
    }

    __syncthreads();   // everyone done reading sH fragments -> reuse as x1 tile

    // ---------------- x1 = relu(mm2) -> bf16 tile in sH ----------------
    #pragma unroll
    for (int c = 0; c < 2; ++c) {
        const int j = (2 * wave + c) * 16 + l16;
        const float bj = b1[j] + b2[j];
        #pragma unroll
        for (int r = 0; r < 4; ++r) {
            #pragma unroll
            for (int g = 0; g < 4; ++g) {
                const int nl = r * 16 + quad * 4 + g;
                float val = fmaxf(acc[r][c][g] + bj, 0.f);
                sH[nl * PITCH + j] = bf16_rne(val);
            }
        }
    }
    __syncthreads();

    // ---------------- row L2-norms from the bf16 x1 tile ----------------
    #pragma unroll
    for (int rg = 0; rg < 2; ++rg) {
        const int row = rg * 32 + (tid >> 3);
        const int c0  = (tid & 7) * 16;
        union { short8 s; unsigned short u[8]; } a, b;
        a.s = *(short8*)&sH[row * PITCH + c0];
        b.s = *(short8*)&sH[row * PITCH + c0 + 8];
        float ss = 0.f;
        #pragma unroll
        for (int i = 0; i < 8; ++i) {
            float fa = bf16_to_f32(a.u[i]);
            float fb = bf16_to_f32(b.u[i]);
            ss = fmaf(fa, fa, fmaf(fb, fb, ss));
        }
        ss += __shfl_xor(ss, 1);
        ss += __shfl_xor(ss, 2);
        ss += __shfl_xor(ss, 4);
        if ((tid & 7) == 0) sNorm[row] = 1.0f / fmaxf(sqrtf(ss), 1e-12f);
    }
    __syncthreads();

    // ---------------- pool MFMA over x1 (norm folded in epilogue) ------
    f32x4 acc2[4][2];
    #pragma unroll
    for (int r = 0; r < 4; ++r)
        #pragma unroll
        for (int c = 0; c < 2; ++c) {
            f32x4 z = {0.f, 0.f, 0.f, 0.f};
            acc2[r][c] = z;
        }

    #pragma unroll
    for (int t = 0; t < 4; ++t) {
        short8 Ah[4];
        #pragma unroll
        for (int r = 0; r < 4; ++r)
            Ah[r] = *(const short8*)&sH[(r * 16 + l16) * PITCH + t * 32 + quad * 8];
        #pragma unroll
        for (int c = 0; c < 2; ++c)
            #pragma unroll
            for (int r = 0; r < 4; ++r) {
                acc2[r][c] = __builtin_amdgcn_mfma_f32_16x16x32_bf16(Ah[r], Ph[c][t], acc2[r][c], 0, 0, 0);
                acc2[r][c] = __builtin_amdgcn_mfma_f32_16x16x32_bf16(Ah[r], Pl[c][t], acc2[r][c], 0, 0, 0);
            }
    }

    __syncthreads();   // sA reads long done; reuse as h2 stage
    #pragma unroll
    for (int c = 0; c < 2; ++c) {
        const int j = (2 * wave + c) * 16 + l16;
        const float pbj = pb[j];
        #pragma unroll
        for (int r = 0; r < 4; ++r) {
            #pragma unroll
            for (int g = 0; g < 4; ++g) {
                const int nl = r * 16 + quad * 4 + g;
                float s = sNorm[nl];
                float val = fmaxf(fmaf(acc2[r][c][g], s, pbj), 0.f);
                sA[nl * PITCH + j] = bf16_rne(val);
            }
        }
    }
    __syncthreads();
    #pragma unroll
    for (int rg = 0; rg < 2; ++rg) {
        const int row = rg * 32 + (tid >> 3);
        const int c0  = (tid & 7) * 16;
        const int n   = tile * 64 + row;
        if (n < N) {
            const int base = row * PITCH + c0;
            *(short8*)&hout[(size_t)n * FF + c0]     = *(short8*)&sA[base];
            *(short8*)&hout[(size_t)n * FF + c0 + 8] = *(short8*)&sA[base + 8];
        }
    }
}

// ---------------------------------------------------------------------------
// Final mm2 (layer 1): out[n][j] = h@W1 + agg@W2 + b1+b2, fp32, LDS-staged
// coalesced stores. Row-major inputs. T14 stage split as above.
// ---------------------------------------------------------------------------
#define OPITCH 68
__global__ __launch_bounds__(256, 2)
void mm2_final_kernel(const unsigned short* __restrict__ hin,
                      const unsigned short* __restrict__ aggh,
                      const unsigned short* __restrict__ W1h, const unsigned short* __restrict__ W1l,
                      const unsigned short* __restrict__ W2h, const unsigned short* __restrict__ W2l,
                      const float* __restrict__ b1, const float* __restrict__ b2,
                      float* __restrict__ out, int N)
{
    __shared__ unsigned short sH[64 * PITCH];
    __shared__ unsigned short sA[64 * PITCH];

    const int tid  = threadIdx.x;
    const int tile = blockIdx.x;
    const int lane = tid & 63, wave = tid >> 6;
    const int quad = lane >> 4, l16 = lane & 15;

    // ---- T14: tile loads into regs first ----
    short8 hreg[2][2], areg[2][2];
    #pragma unroll
    for (int rg = 0; rg < 2; ++rg) {
        const int row = rg * 32 + (tid >> 3);
        const int c0  = (tid & 7) * 16;
        const int n   = tile * 64 + row;
        short8 z = {0,0,0,0,0,0,0,0};
        hreg[rg][0] = z; hreg[rg][1] = z;
        areg[rg][0] = z; areg[rg][1] = z;
        if (n < N) {
            const short8* ph = (const short8*)(hin  + (size_t)n * FF + c0);
            const short8* pa = (const short8*)(aggh + (size_t)n * FF + c0);
            hreg[rg][0] = ph[0]; hreg[rg][1] = ph[1];
            areg[rg][0] = pa[0]; areg[rg][1] = pa[1];
        }
    }

    // ---- B-frag loads (L2) overlap the tile-load latency ----
    short8 B1hf[4], B1lf[4], B2hf[4], B2lf[4];
    #pragma unroll
    for (int t = 0; t < 4; ++t) {
        const size_t o = ((size_t)(wave * 4 + t) * 64 + lane) * 8;
        B1hf[t] = *(const short8*)&W1h[o];
        B1lf[t] = *(const short8*)&W1l[o];
        B2hf[t] = *(const short8*)&W2h[o];
        B2lf[t] = *(const short8*)&W2l[o];
    }

    #pragma unroll
    for (int rg = 0; rg < 2; ++rg) {
        const int row = rg * 32 + (tid >> 3);
        const int base = row * PITCH + (tid & 7) * 16;
        *(short8*)&sH[base]     = hreg[rg][0];
        *(short8*)&sH[base + 8] = hreg[rg][1];
        *(short8*)&sA[base]     = areg[rg][0];
        *(short8*)&sA[base + 8] = areg[rg][1];
    }
    __syncthreads();

    f32x4 acc[4];
    #pragma unroll
    for (int r = 0; r < 4; ++r) {
        f32x4 z = {0.f, 0.f, 0.f, 0.f};
        acc[r] = z;
    }

    #pragma unroll
    for (int t = 0; t < 4; ++t) {
        short8 Hf[4], AH[4];
        #pragma unroll
        for (int r = 0; r < 4; ++r) {
            const int off = (r * 16 + l16) * PITCH + t * 32 + quad * 8;
            Hf[r] = *(const short8*)&sH[off];
            AH[r] = *(const short8*)&sA[off];
        }
        #pragma unroll
        for (int r = 0; r < 4; ++r) {
            acc[r] = __builtin_amdgcn_mfma_f32_16x16x32_bf16(Hf[r], B1hf[t], acc[r], 0, 0, 0);
            acc[r] = __builtin_amdgcn_mfma_f32_16x16x32_bf16(Hf[r], B1lf[t], acc[r], 0, 0, 0);
            acc[r] = __builtin_amdgcn_mfma_f32_16x16x32_bf16(AH[r], B2hf[t], acc[r], 0, 0, 0);
            acc[r] = __builtin_amdgcn_mfma_f32_16x16x32_bf16(AH[r], B2lf[t], acc[r], 0, 0, 0);
        }
    }

    __syncthreads();
    float* sOut = (float*)sH;
    {
        const int j = wave * 16 + l16;
        const float bj = b1[j] + b2[j];
        #pragma unroll
        for (int r = 0; r < 4; ++r) {
            #pragma unroll
            for (int g = 0; g < 4; ++g) {
                const int nl = r * 16 + quad * 4 + g;
                sOut[nl * OPITCH + j] = acc[r][g] + bj;
            }
        }
    }
    __syncthreads();
    {
        const int row = tid >> 2;
        const int seg = tid & 3;
        const int n = tile * 64 + row;
        if (n < N) {
            const float4* src = (const float4*)&sOut[row * OPITCH + seg * 16];
            float4* dst = (float4*)&out[(size_t)n * 64 + seg * 16];
            #pragma unroll
            for (int i = 0; i < 4; ++i) dst[i] = src[i];
        }
    }
}

// ---------------------------------------------------------------------------
extern "C" void kernel_launch(void* const* d_in, const int* in_sizes, int n_in,
                              void* d_out, int out_size, void* d_ws, size_t ws_size,
                              hipStream_t stream) {
    const float* x    = (const float*)d_in[0];
    const int*   esrc = (const int*)d_in[1];
    const int*   edst = (const int*)d_in[2];
    const float* eval = (const float*)d_in[3];
    const float* pw0  = (const float*)d_in[4];
    const float* pb0  = (const float*)d_in[5];
    const float* f1w0 = (const float*)d_in[6];
    const float* f1b0 = (const float*)d_in[7];
    const float* f2w0 = (const float*)d_in[8];
    const float* f2b0 = (const float*)d_in[9];
    const float* pw1  = (const float*)d_in[10];
    const float* pb1  = (const float*)d_in[11];
    const float* f1w1 = (const float*)d_in[12];
    const float* f1b1 = (const float*)d_in[13];
    const float* f2w1 = (const float*)d_in[14];
    const float* f2b1 = (const float*)d_in[15];
    float* out = (float*)d_out;

    const int N = in_sizes[0] / FF;     // 50000  (must be <= 65536 for 16-bit packing)
    const int E = in_sizes[1];          // 800000
    const int nbuck = (N + 255) / 256;  // 196

    char* ws = (char*)d_ws;
    const size_t planesz = (size_t)N * FF * 2;                    // 12.8 MB bf16 plane
    const size_t A = 256;
    size_t off = 0;
    unsigned short* h    = (unsigned short*)(ws + off); off += (planesz + A - 1) / A * A;
    unsigned short* h2   = (unsigned short*)(ws + off); off += (planesz + A - 1) / A * A;
    unsigned short* aggh = (unsigned short*)(ws + off); off += (planesz + A - 1) / A * A;
    int* offsets = (int*)(ws + off); off += ((size_t)(N + 1) * 4 + A - 1) / A * A;
    int* bucket_cnt = (int*)(ws + off); off += (size_t)256 * BSTRIDE * 4;
    int2* ebuf  = (int2*)(ws + off); off += (size_t)nbuck * BCAP * 8;   // 12.8 MB
    int2* edata = (int2*)(ws + off); off += (size_t)E * 8;
    const int wsz[6] = {128 * FF, 128 * FF, 128 * FF, 128 * FF, 64 * FF, 64 * FF};
    unsigned short* whi[6];
    unsigned short* wlo[6];
    for (int i = 0; i < 6; ++i) {
        whi[i] = (unsigned short*)(ws + off); off += (size_t)wsz[i] * 2;
        wlo[i] = (unsigned short*)(ws + off); off += (size_t)wsz[i] * 2;
    }

    WPack pack;
    const float* wsrc[6] = {pw0, f1w0, f2w0, pw1, f1w1, f2w1};
    int wtotal = 0;
    for (int i = 0; i < 6; ++i) {
        pack.src[i] = wsrc[i]; pack.hi[i] = whi[i]; pack.lo[i] = wlo[i]; pack.n[i] = wsz[i];
        wtotal += wsz[i];
    }

    const int ntiles     = (N + 63) / 64;
    const int nodeblocks = (N + 3) / 4;           // 4 waves/block, 1 node per wave
    const int nchunks    = (E + CHUNK - 1) / CHUNK;
    dim3 B(256);

    // ---- 1: weight prep (fragment-major bf16 split) + bucket_cnt zero ----
    wprep_kernel<<<(wtotal + 255) / 256, B, 0, stream>>>(pack, bucket_cnt);

    // ---- 2: fused partA + pool layer 0 -> h (row-major), ebuf ----
    poolpartA_kernel<<<nchunks + ntiles, B, 0, stream>>>(
        x, whi[0], wlo[0], pb0, h, esrc, edst, eval, bucket_cnt, ebuf, N, E, nchunks);

    // ---- 3: partB (dst-sorted edata + offsets) ----
    partB_kernel<<<nbuck, B, 0, stream>>>(bucket_cnt, ebuf, offsets, edata, N, E, nbuck);

    // ---- 4: agg layer 0 (wave-per-node, zero divergence) ----
    agg_kernel<<<nodeblocks, B, 0, stream>>>(h, offsets, edata, aggh, N);

    // ---- 5: fused mm2 layer 0 + pool layer 1 -> h2 ----
    mm2pool_kernel<<<ntiles, B, 0, stream>>>(
        h, aggh, whi[1], wlo[1], whi[2], wlo[2], f1b0, f2b0,
        whi[3], wlo[3], pb1, h2, N);

    // ---- 6: agg layer 1 ----
    agg_kernel<<<nodeblocks, B, 0, stream>>>(h2, offsets, edata, aggh, N);

    // ---- 7: final mm2 layer 1 -> out (fp32) ----
    mm2_final_kernel<<<ntiles, B, 0, stream>>>(
        h2, aggh, whi[4], wlo[4], whi[5], wlo[5], f1b1, f2b1, out, N);
}